// Round 2
// baseline (385.013 us; speedup 1.0000x reference)
//
#include <hip/hip_runtime.h>
#include <math.h>

#define HID 50
#define NPTS 8192
#define NPARA 5000
#define NLAYERS 4

#define BLOCK 512
#define WPB   8            // waves per block
#define GRID  512          // 4096 waves total -> exactly 2 points per wave

// Weight LDS arrays padded so lanes 50..63 read in-bounds (garbage values are
// finite and never used: masked at the output reduction).
#define SWIN_SZ (3*HID + 16)
#define SBIN_SZ (HID + 16)
#define SWH_SZ  (NLAYERS*HID*HID + 16)
#define SBH_SZ  (NLAYERS*HID + 16)
#define SWO_SZ  (2*64)
#define ST_STRIDE 8        // floats per k-row of state (6 used + 2 pad, 32B aligned)

__device__ __forceinline__ float fast_tanh(float x) {
    // tanh(x) = sign(x) * (1 - 2/(exp(2|x|)+1)); exp->inf gives exactly 1.
    const float ax = __builtin_fabsf(x);
    const float e  = __expf(2.0f * ax);
    const float r  = __builtin_amdgcn_rcpf(e + 1.0f);
    const float t  = fmaf(-2.0f, r, 1.0f);
    return __builtin_copysignf(t, x);
}

__global__ __launch_bounds__(BLOCK, 4) void point_kernel(
    const float* __restrict__ x,
    const float* __restrict__ W_in, const float* __restrict__ b_in,
    const float* __restrict__ W_hid, const float* __restrict__ b_hid,
    const float* __restrict__ W_out, const float* __restrict__ b_out,
    double* __restrict__ sums)
{
    __shared__ float sWin[SWIN_SZ];
    __shared__ float sbin[SBIN_SZ];
    __shared__ float sWh[SWH_SZ];
    __shared__ float sbh[SBH_SZ];
    __shared__ float sWo[SWO_SZ];
    __shared__ float sbo[2];
    __shared__ float sSt[WPB][52 * ST_STRIDE];   // per-wave state broadcast buffer

    const int tid = threadIdx.x;
    for (int i = tid; i < 3*HID; i += BLOCK) sWin[i] = W_in[i];
    for (int i = 3*HID + tid; i < SWIN_SZ; i += BLOCK) sWin[i] = 0.f;
    for (int i = tid; i < HID; i += BLOCK) sbin[i] = b_in[i];
    for (int i = HID + tid; i < SBIN_SZ; i += BLOCK) sbin[i] = 0.f;
    for (int i = tid; i < NLAYERS*HID*HID; i += BLOCK) sWh[i] = W_hid[i];
    for (int i = NLAYERS*HID*HID + tid; i < SWH_SZ; i += BLOCK) sWh[i] = 0.f;
    for (int i = tid; i < NLAYERS*HID; i += BLOCK) sbh[i] = b_hid[i];
    for (int i = NLAYERS*HID + tid; i < SBH_SZ; i += BLOCK) sbh[i] = 0.f;
    for (int i = tid; i < 2*HID; i += BLOCK) sWo[i] = W_out[i];
    for (int i = 2*HID + tid; i < SWO_SZ; i += BLOCK) sWo[i] = 0.f;
    if (tid < 2) sbo[tid] = b_out[tid];
    __syncthreads();

    const int lane  = tid & 63;
    const int wave  = tid >> 6;
    const int gwave = blockIdx.x * WPB + wave;
    const int nwave = GRID * WPB;
    float* __restrict__ st = sSt[wave];

    double a0 = 0.0, a1 = 0.0, a2 = 0.0, a3 = 0.0, a4 = 0.0, a5 = 0.0;

    for (int p = gwave; p < NPTS; p += nwave) {
        const float x0 = x[3*p+0], x1 = x[3*p+1], x2 = x[3*p+2];

        // ---- input layer ----
        const float w0 = sWin[lane];
        const float w1 = sWin[HID + lane];
        const float w2 = sWin[2*HID + lane];
        float z = fmaf(x0, w0, fmaf(x1, w1, fmaf(x2, w2, sbin[lane])));
        float h = fast_tanh(z);
        float s = 1.f - h*h;
        float hx = s*w0, hy = s*w1, ht = s*w2;
        float hxx = -2.f*h*s*w0*w0;
        float hyy = -2.f*h*s*w1*w1;

        // ---- hidden layers ----
        for (int l = 0; l < NLAYERS; ++l) {
            // stage this layer's input state for wave-uniform broadcast reads
            if (lane < HID) {
                float4* p4 = (float4*)&st[lane * ST_STRIDE];
                *p4 = make_float4(h, hx, hy, ht);
                float2* p2 = (float2*)&st[lane * ST_STRIDE + 4];
                *p2 = make_float2(hxx, hyy);
            }
            const float* __restrict__ Wl = &sWh[l*HID*HID];
            float za  = sbh[l*HID + lane];
            float zx = 0.f, zy = 0.f, zt = 0.f, zxx = 0.f, zyy = 0.f;
            #pragma unroll 10
            for (int k = 0; k < HID; ++k) {
                const float w = Wl[k*HID + lane];               // lane-strided, conflict-free
                const float4 s4 = *(const float4*)&st[k*ST_STRIDE];     // broadcast
                const float2 s2 = *(const float2*)&st[k*ST_STRIDE + 4]; // broadcast
                za  = fmaf(s4.x, w, za);
                zx  = fmaf(s4.y, w, zx);
                zy  = fmaf(s4.z, w, zy);
                zt  = fmaf(s4.w, w, zt);
                zxx = fmaf(s2.x, w, zxx);
                zyy = fmaf(s2.y, w, zyy);
            }
            const float hn = fast_tanh(za);
            const float sn = 1.f - hn*hn;
            hxx = fmaf(sn, zxx, -2.f*hn*sn*zx*zx);
            hyy = fmaf(sn, zyy, -2.f*hn*sn*zy*zy);
            hx = sn*zx; hy = sn*zy; ht = sn*zt;
            h = hn;
        }

        // ---- output layer partials + wave reduction ----
        const float wo0 = sWo[lane*2+0];
        const float wo1 = sWo[lane*2+1];
        const bool act = (lane < HID);
        float pu   = act ? h  *wo0 : 0.f;
        float pv   = act ? h  *wo1 : 0.f;
        float put  = act ? ht *wo0 : 0.f;
        float pvt  = act ? ht *wo1 : 0.f;
        float puxx = act ? hxx*wo0 : 0.f;
        float pvxx = act ? hxx*wo1 : 0.f;
        float puyy = act ? hyy*wo0 : 0.f;
        float pvyy = act ? hyy*wo1 : 0.f;
        #pragma unroll
        for (int off = 32; off > 0; off >>= 1) {
            pu   += __shfl_xor(pu,   off);
            pv   += __shfl_xor(pv,   off);
            put  += __shfl_xor(put,  off);
            pvt  += __shfl_xor(pvt,  off);
            puxx += __shfl_xor(puxx, off);
            pvxx += __shfl_xor(pvxx, off);
            puyy += __shfl_xor(puyy, off);
            pvyy += __shfl_xor(pvyy, off);
        }
        const float u = pu + sbo[0];
        const float v = pv + sbo[1];
        const float Q = u*u + v*v;
        const float g1 = pvt - 0.5f*puxx - 0.5f*pvyy - Q*u + v;   // base1
        const float g2 = put + 0.5f*pvxx - 0.5f*puyy + Q*v + u;   // base2
        const float h1 = 0.5f*puyy, h2 = 0.5f*pvyy;
        const float k1 = Q*v,       k2 = Q*u;

        // f1 = g1 - a*h1 - cc*k1 ; f2 = g2 + a*h2 - cc*k2
        // mean(f1^2+f2^2) = (S0 + a^2 S1 + cc^2 S2 + 2a S3 - 2cc S4 + 2a cc S5)/N
        a0 += (double)g1*(double)g1 + (double)g2*(double)g2;
        a1 += (double)h1*(double)h1 + (double)h2*(double)h2;
        a2 += (double)k1*(double)k1 + (double)k2*(double)k2;
        a3 += (double)g2*(double)h2 - (double)g1*(double)h1;
        a4 += (double)g1*(double)k1 + (double)g2*(double)k2;
        a5 += (double)h1*(double)k1 - (double)h2*(double)k2;
    }

    if (lane == 0) {
        atomicAdd(&sums[0], a0);
        atomicAdd(&sums[1], a1);
        atomicAdd(&sums[2], a2);
        atomicAdd(&sums[3], a3);
        atomicAdd(&sums[4], a4);
        atomicAdd(&sums[5], a5);
    }
}

__global__ __launch_bounds__(256) void para_kernel(
    const float* __restrict__ para,
    const double* __restrict__ sums,
    float* __restrict__ out)
{
    const int p = blockIdx.x * 256 + threadIdx.x;
    if (p >= NPARA) return;
    const double a  = (double)para[3*p+0];
    const double cc = (double)para[3*p+2];
    const double r = sums[0]
                   + a*a*sums[1]
                   + cc*cc*sums[2]
                   + 2.0*a*sums[3]
                   - 2.0*cc*sums[4]
                   + 2.0*a*cc*sums[5];
    out[p] = (float)(r * (1.0 / (double)NPTS));
}

extern "C" void kernel_launch(void* const* d_in, const int* in_sizes, int n_in,
                              void* d_out, int out_size, void* d_ws, size_t ws_size,
                              hipStream_t stream) {
    const float* x     = (const float*)d_in[0];
    const float* para  = (const float*)d_in[1];
    const float* W_in  = (const float*)d_in[2];
    const float* b_in  = (const float*)d_in[3];
    const float* W_hid = (const float*)d_in[4];
    const float* b_hid = (const float*)d_in[5];
    const float* W_out = (const float*)d_in[6];
    const float* b_out = (const float*)d_in[7];
    double* sums = (double*)d_ws;

    hipMemsetAsync(sums, 0, 6*sizeof(double), stream);
    point_kernel<<<GRID, BLOCK, 0, stream>>>(x, W_in, b_in, W_hid, b_hid,
                                             W_out, b_out, sums);
    para_kernel<<<(NPARA + 255)/256, 256, 0, stream>>>(para, sums, (float*)d_out);
}

// Round 3
// 109.694 us; speedup vs baseline: 3.5099x; 3.5099x over previous
//
#include <hip/hip_runtime.h>
#include <math.h>

#define HID 50
#define NPTS 8192
#define NPARA 5000
#define NLAYERS 4

#define BLOCK 512
#define WPB   8            // waves per block
#define GRID  512          // 4096 waves; each register-blocks 2 points

// Weight LDS arrays padded so lanes 50..63 read in-bounds (values finite,
// never broadcast, masked at the output reduction).
#define SWIN_SZ (3*HID + 16)
#define SBIN_SZ (HID + 16)
#define SWH_SZ  (NLAYERS*HID*HID + 16)
#define SBH_SZ  (NLAYERS*HID + 16)
#define SWO_SZ  (2*64)

__device__ __forceinline__ float fast_tanh(float x) {
    const float ax = __builtin_fabsf(x);
    const float e  = __expf(2.0f * ax);
    const float r  = __builtin_amdgcn_rcpf(e + 1.0f);
    const float t  = fmaf(-2.0f, r, 1.0f);
    return __builtin_copysignf(t, x);
}

// Broadcast lane k's value to all lanes via the VALU (v_readlane -> SGPR),
// avoiding the LDS pipe entirely. k is a literal after full unroll.
__device__ __forceinline__ float readlane_f(float v, int k) {
    return __int_as_float(__builtin_amdgcn_readlane(__float_as_int(v), k));
}

__global__ __launch_bounds__(BLOCK, 4) void point_kernel(
    const float* __restrict__ x,
    const float* __restrict__ W_in, const float* __restrict__ b_in,
    const float* __restrict__ W_hid, const float* __restrict__ b_hid,
    const float* __restrict__ W_out, const float* __restrict__ b_out,
    double* __restrict__ sums)
{
    __shared__ float sWin[SWIN_SZ];
    __shared__ float sbin[SBIN_SZ];
    __shared__ float sWh[SWH_SZ];
    __shared__ float sbh[SBH_SZ];
    __shared__ float sWo[SWO_SZ];
    __shared__ float sbo[2];
    __shared__ double sRed[WPB][6];

    const int tid = threadIdx.x;
    for (int i = tid; i < 3*HID; i += BLOCK) sWin[i] = W_in[i];
    for (int i = 3*HID + tid; i < SWIN_SZ; i += BLOCK) sWin[i] = 0.f;
    for (int i = tid; i < HID; i += BLOCK) sbin[i] = b_in[i];
    for (int i = HID + tid; i < SBIN_SZ; i += BLOCK) sbin[i] = 0.f;
    for (int i = tid; i < NLAYERS*HID*HID; i += BLOCK) sWh[i] = W_hid[i];
    for (int i = NLAYERS*HID*HID + tid; i < SWH_SZ; i += BLOCK) sWh[i] = 0.f;
    for (int i = tid; i < NLAYERS*HID; i += BLOCK) sbh[i] = b_hid[i];
    for (int i = NLAYERS*HID + tid; i < SBH_SZ; i += BLOCK) sbh[i] = 0.f;
    for (int i = tid; i < 2*HID; i += BLOCK) sWo[i] = W_out[i];
    for (int i = 2*HID + tid; i < SWO_SZ; i += BLOCK) sWo[i] = 0.f;
    if (tid < 2) sbo[tid] = b_out[tid];
    __syncthreads();

    const int lane  = tid & 63;
    const int wave  = tid >> 6;
    const int gwave = blockIdx.x * WPB + wave;
    const int NW    = GRID * WPB;            // 4096
    const int pA = gwave;                    // point A
    const int pB = gwave + NW;               // point B (always < NPTS: 2*4096)

    double a0 = 0.0, a1 = 0.0, a2 = 0.0, a3 = 0.0, a4 = 0.0, a5 = 0.0;

    const float xA0 = x[3*pA+0], xA1 = x[3*pA+1], xA2 = x[3*pA+2];
    const float xB0 = x[3*pB+0], xB1 = x[3*pB+1], xB2 = x[3*pB+2];

    // ---- input layer (both points) ----
    const float w0 = sWin[lane];
    const float w1 = sWin[HID + lane];
    const float w2 = sWin[2*HID + lane];
    const float bi = sbin[lane];

    float zA = fmaf(xA0, w0, fmaf(xA1, w1, fmaf(xA2, w2, bi)));
    float hA = fast_tanh(zA);
    float sA = 1.f - hA*hA;
    float hxA = sA*w0, hyA = sA*w1, htA = sA*w2;
    float hxxA = -2.f*hA*sA*w0*w0;
    float hyyA = -2.f*hA*sA*w1*w1;

    float zB = fmaf(xB0, w0, fmaf(xB1, w1, fmaf(xB2, w2, bi)));
    float hB = fast_tanh(zB);
    float sB = 1.f - hB*hB;
    float hxB = sB*w0, hyB = sB*w1, htB = sB*w2;
    float hxxB = -2.f*hB*sB*w0*w0;
    float hyyB = -2.f*hB*sB*w1*w1;

    // ---- hidden layers ----
    for (int l = 0; l < NLAYERS; ++l) {
        const float* __restrict__ Wl = &sWh[l*HID*HID];
        const float bl = sbh[l*HID + lane];
        float zaA = bl, zxA = 0.f, zyA = 0.f, ztA = 0.f, zxxA = 0.f, zyyA = 0.f;
        float zaB = bl, zxB = 0.f, zyB = 0.f, ztB = 0.f, zxxB = 0.f, zyyB = 0.f;
        #pragma unroll
        for (int k = 0; k < HID; ++k) {
            const float w = Wl[k*HID + lane];   // lane-strided ds_read_b32, conflict-free
            zaA  = fmaf(readlane_f(hA,   k), w, zaA);
            zxA  = fmaf(readlane_f(hxA,  k), w, zxA);
            zyA  = fmaf(readlane_f(hyA,  k), w, zyA);
            ztA  = fmaf(readlane_f(htA,  k), w, ztA);
            zxxA = fmaf(readlane_f(hxxA, k), w, zxxA);
            zyyA = fmaf(readlane_f(hyyA, k), w, zyyA);
            zaB  = fmaf(readlane_f(hB,   k), w, zaB);
            zxB  = fmaf(readlane_f(hxB,  k), w, zxB);
            zyB  = fmaf(readlane_f(hyB,  k), w, zyB);
            ztB  = fmaf(readlane_f(htB,  k), w, ztB);
            zxxB = fmaf(readlane_f(hxxB, k), w, zxxB);
            zyyB = fmaf(readlane_f(hyyB, k), w, zyyB);
        }
        float hn = fast_tanh(zaA);
        float sn = 1.f - hn*hn;
        hxxA = fmaf(sn, zxxA, -2.f*hn*sn*zxA*zxA);
        hyyA = fmaf(sn, zyyA, -2.f*hn*sn*zyA*zyA);
        hxA = sn*zxA; hyA = sn*zyA; htA = sn*ztA; hA = hn;

        hn = fast_tanh(zaB);
        sn = 1.f - hn*hn;
        hxxB = fmaf(sn, zxxB, -2.f*hn*sn*zxB*zxB);
        hyyB = fmaf(sn, zyyB, -2.f*hn*sn*zyB*zyB);
        hxB = sn*zxB; hyB = sn*zyB; htB = sn*ztB; hB = hn;
    }

    // ---- output layer partials + wave reduction (per point) ----
    const float wo0 = sWo[lane*2+0];
    const float wo1 = sWo[lane*2+1];
    const bool act = (lane < HID);

    #pragma unroll
    for (int pt = 0; pt < 2; ++pt) {
        const float h_  = pt ? hB  : hA;
        const float ht_ = pt ? htB : htA;
        const float hxx_= pt ? hxxB: hxxA;
        const float hyy_= pt ? hyyB: hyyA;

        float pu   = act ? h_  *wo0 : 0.f;
        float pv   = act ? h_  *wo1 : 0.f;
        float put  = act ? ht_ *wo0 : 0.f;
        float pvt  = act ? ht_ *wo1 : 0.f;
        float puxx = act ? hxx_*wo0 : 0.f;
        float pvxx = act ? hxx_*wo1 : 0.f;
        float puyy = act ? hyy_*wo0 : 0.f;
        float pvyy = act ? hyy_*wo1 : 0.f;
        #pragma unroll
        for (int off = 32; off > 0; off >>= 1) {
            pu   += __shfl_xor(pu,   off);
            pv   += __shfl_xor(pv,   off);
            put  += __shfl_xor(put,  off);
            pvt  += __shfl_xor(pvt,  off);
            puxx += __shfl_xor(puxx, off);
            pvxx += __shfl_xor(pvxx, off);
            puyy += __shfl_xor(puyy, off);
            pvyy += __shfl_xor(pvyy, off);
        }
        const float u = pu + sbo[0];
        const float v = pv + sbo[1];
        const float Q = u*u + v*v;
        const float g1 = pvt - 0.5f*puxx - 0.5f*pvyy - Q*u + v;   // base1
        const float g2 = put + 0.5f*pvxx - 0.5f*puyy + Q*v + u;   // base2
        const float h1 = 0.5f*puyy, h2 = 0.5f*pvyy;
        const float k1 = Q*v,       k2 = Q*u;

        a0 += (double)g1*(double)g1 + (double)g2*(double)g2;
        a1 += (double)h1*(double)h1 + (double)h2*(double)h2;
        a2 += (double)k1*(double)k1 + (double)k2*(double)k2;
        a3 += (double)g2*(double)h2 - (double)g1*(double)h1;
        a4 += (double)g1*(double)k1 + (double)g2*(double)k2;
        a5 += (double)h1*(double)k1 - (double)h2*(double)k2;
    }

    // ---- block-level reduction: one atomic set per block ----
    if (lane == 0) {
        sRed[wave][0] = a0; sRed[wave][1] = a1; sRed[wave][2] = a2;
        sRed[wave][3] = a3; sRed[wave][4] = a4; sRed[wave][5] = a5;
    }
    __syncthreads();
    if (tid < 6) {
        double t = 0.0;
        #pragma unroll
        for (int wv = 0; wv < WPB; ++wv) t += sRed[wv][tid];
        atomicAdd(&sums[tid], t);
    }
}

__global__ __launch_bounds__(256) void para_kernel(
    const float* __restrict__ para,
    const double* __restrict__ sums,
    float* __restrict__ out)
{
    const int p = blockIdx.x * 256 + threadIdx.x;
    if (p >= NPARA) return;
    const double a  = (double)para[3*p+0];
    const double cc = (double)para[3*p+2];
    const double r = sums[0]
                   + a*a*sums[1]
                   + cc*cc*sums[2]
                   + 2.0*a*sums[3]
                   - 2.0*cc*sums[4]
                   + 2.0*a*cc*sums[5];
    out[p] = (float)(r * (1.0 / (double)NPTS));
}

extern "C" void kernel_launch(void* const* d_in, const int* in_sizes, int n_in,
                              void* d_out, int out_size, void* d_ws, size_t ws_size,
                              hipStream_t stream) {
    const float* x     = (const float*)d_in[0];
    const float* para  = (const float*)d_in[1];
    const float* W_in  = (const float*)d_in[2];
    const float* b_in  = (const float*)d_in[3];
    const float* W_hid = (const float*)d_in[4];
    const float* b_hid = (const float*)d_in[5];
    const float* W_out = (const float*)d_in[6];
    const float* b_out = (const float*)d_in[7];
    double* sums = (double*)d_ws;

    hipMemsetAsync(sums, 0, 6*sizeof(double), stream);
    point_kernel<<<GRID, BLOCK, 0, stream>>>(x, W_in, b_in, W_hid, b_hid,
                                             W_out, b_out, sums);
    para_kernel<<<(NPARA + 255)/256, 256, 0, stream>>>(para, sums, (float*)d_out);
}